// Round 4
// baseline (394.125 us; speedup 1.0000x reference)
//
#include <hip/hip_runtime.h>
#include <hip/hip_bf16.h>
#include <math.h>

#define LN_EPS 1e-5f
// dim^-0.5 * log2(e): folded into q so softmax is exp2(s) with no muls
#define QSCALE 0.09016844005556021f

typedef __attribute__((ext_vector_type(8))) short short8;
typedef __attribute__((ext_vector_type(4))) short short4v;
typedef __attribute__((ext_vector_type(4))) float f32x4;

__device__ inline ushort f2bf(float f) {
  __hip_bfloat16 h = __float2bfloat16(f);
  return *reinterpret_cast<ushort*>(&h);
}

// pack two positive fp32 into bf16 pair (lo=a, hi=b): +0x8000 then v_perm.
// (hardware-verified; do NOT swap for cvt_pk asm)
__device__ inline uint pk2bf(float a, float b) {
  uint ua = __float_as_uint(a) + 0x8000u;
  uint ub = __float_as_uint(b) + 0x8000u;
  return __builtin_amdgcn_perm(ub, ua, 0x07060302u);
}

// Shapes (fixed): b=8, n=2048/stream, 3 streams, dim=256, heads=8, d=32.
// xn (bf16): [8*6144][256].  q/k (bf16): [bh][2048][32].
// vT2 (bf16, FRAGMENT layout): [bh][32 tiles][2 dh][4 t4][64 lane][4] --
//   element = V[key = tile*64 + t4*16 + (lane>>4)*4 + j][d = dh*16 + (lane&15)]
//   i.e. exactly the 16x16x16bf16 B-fragment each attn lane needs: attn loads
//   it with coalesced 8B/lane global loads, NO LDS staging at all.
// osum (bf16): [b*2048][256].

// ---------------------- fused: LN-normalize -> bf16  +  weight cast -> bf16
__global__ __launch_bounds__(256) void ln_wcast_kernel(
    const float* __restrict__ x, const float* __restrict__ lng,
    const float* __restrict__ lnb,
    const float* __restrict__ Wq, const float* __restrict__ Wk,
    const float* __restrict__ Wv, const float* __restrict__ Wo,
    ushort* __restrict__ xn, ushort* __restrict__ wbf) {
  if (blockIdx.x < 256) {
    int t = blockIdx.x * 256 + threadIdx.x;
    int e0 = t * 4;
    int m = e0 >> 16, off = e0 & 65535;
    const float* src = (m == 0) ? Wq : (m == 1) ? Wk : (m == 2) ? Wv : Wo;
    float4 v = *(const float4*)(src + off);
    ushort4 o;
    o.x = f2bf(v.x); o.y = f2bf(v.y); o.z = f2bf(v.z); o.w = f2bf(v.w);
    *(ushort4*)(wbf + m * 65536 + off) = o;
    return;
  }
  int w = threadIdx.x >> 6;
  int lane = threadIdx.x & 63;
  size_t token = (size_t)(blockIdx.x - 256) * 4 + w;
  float4 v = *(const float4*)(x + token * 256 + lane * 4);
  float s  = v.x + v.y + v.z + v.w;
  float s2 = v.x * v.x + v.y * v.y + v.z * v.z + v.w * v.w;
#pragma unroll
  for (int off = 32; off >= 1; off >>= 1) {
    s  += __shfl_xor(s, off, 64);
    s2 += __shfl_xor(s2, off, 64);
  }
  float mu  = s * (1.0f / 256.0f);
  float var = s2 * (1.0f / 256.0f) - mu * mu;
  float rs  = rsqrtf(var + LN_EPS);
  float4 g = *(const float4*)(lng + lane * 4);
  float4 bb = *(const float4*)(lnb + lane * 4);
  ushort4 o;
  o.x = f2bf((v.x - mu) * rs * g.x + bb.x);
  o.y = f2bf((v.y - mu) * rs * g.y + bb.y);
  o.z = f2bf((v.z - mu) * rs * g.z + bb.z);
  o.w = f2bf((v.w - mu) * rs * g.w + bb.w);
  *(ushort4*)(xn + token * 256 + lane * 4) = o;
}

// ------------------------------------------------- QKV projections (MFMA)
// z: 0 = q (stream 0, Wq, scaled, C^T out)
// z: 1 = kv_e, 2 = kv_l: xf loaded ONCE feeds Wk (A-form, C^T) AND Wv
// (B-form, fragment-layout vT2 out).  No LDS; xf double-buffered.
__global__ __launch_bounds__(256) void proj_kernel(
    const ushort* __restrict__ xn,
    const ushort* __restrict__ wq, const ushort* __restrict__ wk,
    const ushort* __restrict__ wv,
    const float* __restrict__ bq, const float* __restrict__ bk,
    const float* __restrict__ bv,
    ushort* __restrict__ qb, ushort* __restrict__ keb, ushort* __restrict__ vTe,
    ushort* __restrict__ klb, ushort* __restrict__ vTl) {
  int z = blockIdx.z;
  int tid = threadIdx.x;
  int w = tid >> 6, lane = tid & 63;
  int n = lane & 15, quad = lane >> 4;
  int cbase = blockIdx.y * 128 + w * 32;
  int b = (blockIdx.x * 128) >> 11;
  int r0 = (blockIdx.x * 128) & 2047;

  if (z == 0) {
    const ushort* xbase = xn + ((size_t)b * 6144 + r0) * 256;
    short8 wf[2][8];
#pragma unroll
    for (int ct = 0; ct < 2; ++ct)
#pragma unroll
      for (int kc = 0; kc < 8; ++kc)
        wf[ct][kc] = *(const short8*)(wq + (size_t)(cbase + ct * 16 + n) * 256 + kc * 32 + quad * 8);
    float4 bt[2];
    bt[0] = *(const float4*)(bq + cbase + quad * 4);
    bt[1] = *(const float4*)(bq + cbase + 16 + quad * 4);

    short8 xfA[8], xfB[8];
#pragma unroll
    for (int kc = 0; kc < 8; ++kc)
      xfA[kc] = *(const short8*)(xbase + (size_t)n * 256 + kc * 32 + quad * 8);

#pragma unroll
    for (int tt = 0; tt < 8; ++tt) {
      const short8* cur = (tt & 1) ? xfB : xfA;
      short8* nxt = (tt & 1) ? xfA : xfB;
      if (tt < 7) {
#pragma unroll
        for (int kc = 0; kc < 8; ++kc)
          nxt[kc] = *(const short8*)(xbase + (size_t)((tt + 1) * 16 + n) * 256 + kc * 32 + quad * 8);
      }
      f32x4 acc[2] = {{0.f, 0.f, 0.f, 0.f}, {0.f, 0.f, 0.f, 0.f}};
#pragma unroll
      for (int ct = 0; ct < 2; ++ct)
#pragma unroll
        for (int kc = 0; kc < 8; ++kc)
          acc[ct] = __builtin_amdgcn_mfma_f32_16x16x32_bf16(wf[ct][kc], cur[kc], acc[ct], 0, 0, 0);
      int n2 = r0 + tt * 16 + n;
#pragma unroll
      for (int ct = 0; ct < 2; ++ct) {
        int c = cbase + ct * 16 + quad * 4;
        int h = c >> 5, d = c & 31;
        float* bp = (float*)&bt[ct];
        ushort4 st;
        st.x = f2bf((acc[ct][0] + bp[0]) * QSCALE);
        st.y = f2bf((acc[ct][1] + bp[1]) * QSCALE);
        st.z = f2bf((acc[ct][2] + bp[2]) * QSCALE);
        st.w = f2bf((acc[ct][3] + bp[3]) * QSCALE);
        *(ushort4*)(qb + (((size_t)(b * 8 + h) * 2048) + n2) * 32 + d) = st;
      }
    }
  } else {
    int s = z;
    ushort* kout = (z == 1) ? keb : klb;
    ushort* vout = (z == 1) ? vTe : vTl;
    const ushort* xbase = xn + ((size_t)b * 6144 + s * 2048 + r0) * 256;
    short8 wfk[2][8], wfv[2][8];
#pragma unroll
    for (int ct = 0; ct < 2; ++ct)
#pragma unroll
      for (int kc = 0; kc < 8; ++kc) {
        wfk[ct][kc] = *(const short8*)(wk + (size_t)(cbase + ct * 16 + n) * 256 + kc * 32 + quad * 8);
        wfv[ct][kc] = *(const short8*)(wv + (size_t)(cbase + ct * 16 + n) * 256 + kc * 32 + quad * 8);
      }
    float4 btk[2];
    btk[0] = *(const float4*)(bk + cbase + quad * 4);
    btk[1] = *(const float4*)(bk + cbase + 16 + quad * 4);
    float bsv[2] = {bv[cbase + n], bv[cbase + 16 + n]};

    short8 xfA[8], xfB[8];
#pragma unroll
    for (int kc = 0; kc < 8; ++kc)
      xfA[kc] = *(const short8*)(xbase + (size_t)n * 256 + kc * 32 + quad * 8);

#pragma unroll
    for (int tt = 0; tt < 8; ++tt) {
      const short8* cur = (tt & 1) ? xfB : xfA;
      short8* nxt = (tt & 1) ? xfA : xfB;
      if (tt < 7) {
#pragma unroll
        for (int kc = 0; kc < 8; ++kc)
          nxt[kc] = *(const short8*)(xbase + (size_t)((tt + 1) * 16 + n) * 256 + kc * 32 + quad * 8);
      }
      f32x4 ack[2] = {{0.f, 0.f, 0.f, 0.f}, {0.f, 0.f, 0.f, 0.f}};
      f32x4 acv[2] = {{0.f, 0.f, 0.f, 0.f}, {0.f, 0.f, 0.f, 0.f}};
#pragma unroll
      for (int ct = 0; ct < 2; ++ct)
#pragma unroll
        for (int kc = 0; kc < 8; ++kc) {
          ack[ct] = __builtin_amdgcn_mfma_f32_16x16x32_bf16(wfk[ct][kc], cur[kc], ack[ct], 0, 0, 0);
          acv[ct] = __builtin_amdgcn_mfma_f32_16x16x32_bf16(cur[kc], wfv[ct][kc], acv[ct], 0, 0, 0);
        }
      // store k: C^T  (lane: token n2, cols quad*4+r)
      int n2 = r0 + tt * 16 + n;
#pragma unroll
      for (int ct = 0; ct < 2; ++ct) {
        int c = cbase + ct * 16 + quad * 4;
        int h = c >> 5, d = c & 31;
        float* bp = (float*)&btk[ct];
        ushort4 st;
        st.x = f2bf(ack[ct][0] + bp[0]);
        st.y = f2bf(ack[ct][1] + bp[1]);
        st.z = f2bf(ack[ct][2] + bp[2]);
        st.w = f2bf(ack[ct][3] + bp[3]);
        *(ushort4*)(kout + (((size_t)(b * 8 + h) * 2048) + n2) * 32 + d) = st;
      }
      // store v: B-fragment layout vT2[bh][tile][dh][t4][lane'][j]
      //   acv regs r=0..3 are keys tq..tq+3 at col c (head h, dim d)
      int tq = r0 + tt * 16 + quad * 4;
      int tile = tq >> 6;
      int t4 = (tq >> 4) & 3;
      int qp = (tq >> 2) & 3;  // quad' of the consuming attn lane
#pragma unroll
      for (int ct = 0; ct < 2; ++ct) {
        int c = cbase + ct * 16 + n;
        int h = c >> 5, d = c & 31;
        int dh = d >> 4, np = d & 15;
        ushort4 st;
        st.x = f2bf(acv[ct][0] + bsv[ct]);
        st.y = f2bf(acv[ct][1] + bsv[ct]);
        st.z = f2bf(acv[ct][2] + bsv[ct]);
        st.w = f2bf(acv[ct][3] + bsv[ct]);
        *(ushort4*)(vout + (size_t)(b * 8 + h) * 65536
                    + (size_t)((((tile * 2 + dh) * 4 + t4) * 64 + qp * 16 + np) * 4)) = st;
      }
    }
  }
}

// ------------------------------------------------ flash attention bf16 MFMA
// gq=1 (64 q-rows/block, grid 2048 = 8 blocks/CU supply): TLP version.
// Round-3 post-mortem: 4 waves/SIMD left the serial chain
// (K-load -> QK -> exp2 -> pack -> PV) stall-bound (MfmaUtil 40, VALU 50,
// HBM 4%). This version trades ILP (register double-buffers, 32 movs/jt)
// for 2x wave supply; per-jt K/V loads are L2-hits hidden by other waves.
// Swizzle: consecutive resident blocks on an XCD share one bh (hot K/V
// working set ~256KB/XCD instead of 4MB).
__global__ __launch_bounds__(256) void attn_kernel(
    const ushort* __restrict__ q,
    const ushort* __restrict__ ke, const ushort* __restrict__ vTe,
    const ushort* __restrict__ kl, const ushort* __restrict__ vTl,
    ushort* __restrict__ osum) {
  int tid = threadIdx.x;
  int w = tid >> 6, lane = tid & 63;
  int n = lane & 15, quad = lane >> 4;

  union { uint2 u; short4v s; } one_u;
  one_u.u.x = 0x3F803F80u; one_u.u.y = 0x3F803F80u;  // bf16 1.0 x4
  const short4v vone = one_u.s;

  // L -> (xcd, idx); all 32 q-chunks of a bh contiguous in idx on one XCD
  int L = blockIdx.y * 8 + blockIdx.x;
  int xcd = L & 7, idx = L >> 3;          // idx in [0,256)
  int bh = xcd + 8 * (idx >> 5);          // 8 bh per XCD, 32 chunks each
  int q0 = (idx & 31) * 64;
  int qbase = q0 + w * 16;

  short8 qfrag = *(const short8*)(q + ((size_t)bh * 2048 + qbase + n) * 32 + quad * 8);

  f32x4 outv[2];
  outv[0] = (f32x4){0.f, 0.f, 0.f, 0.f};
  outv[1] = (f32x4){0.f, 0.f, 0.f, 0.f};

  for (int s = 0; s < 2; ++s) {
    const ushort* K  = (s == 0 ? ke : kl) + (size_t)bh * 2048 * 32;
    const ushort* VT = (s == 0 ? vTe : vTl) + (size_t)bh * 65536;
    f32x4 lacc = (f32x4){0.f, 0.f, 0.f, 0.f};
    f32x4 oacc[2];
    oacc[0] = (f32x4){0.f, 0.f, 0.f, 0.f};
    oacc[1] = (f32x4){0.f, 0.f, 0.f, 0.f};

    for (int jt = 0; jt < 32; ++jt) {
      size_t tb = (size_t)jt * 2048;
      // K fragments (4 x 16B) then V fragments (8 x 8B): compiler's counted
      // vmcnt lets QK start once K lands while V stays in flight.
      short8 kf[4];
#pragma unroll
      for (int t4 = 0; t4 < 4; ++t4)
        kf[t4] = *(const short8*)(K + tb + (size_t)(t4 * 16 + n) * 32 + quad * 8);
      short4v vf[2][4];
#pragma unroll
      for (int dh = 0; dh < 2; ++dh)
#pragma unroll
        for (int t4 = 0; t4 < 4; ++t4)
          vf[dh][t4] = *(const short4v*)(VT + tb + (dh * 4 + t4) * 256 + lane * 4);

      // S^T tiles (16 keys x 16 qrows), K=32 = full head dim
      f32x4 sacc[4];
#pragma unroll
      for (int t4 = 0; t4 < 4; ++t4) {
        f32x4 z = {0.f, 0.f, 0.f, 0.f};
        sacc[t4] = __builtin_amdgcn_mfma_f32_16x16x32_bf16(kf[t4], qfrag, z, 0, 0, 0);
      }
      // p = exp2(s), pack to bf16 A-fragments in-register
      short4v pf[4];
#pragma unroll
      for (int t4 = 0; t4 < 4; ++t4) {
        float p0 = __builtin_amdgcn_exp2f(sacc[t4][0]);
        float p1 = __builtin_amdgcn_exp2f(sacc[t4][1]);
        float p2 = __builtin_amdgcn_exp2f(sacc[t4][2]);
        float p3 = __builtin_amdgcn_exp2f(sacc[t4][3]);
        union { uint2 u; short4v s4; } cv;
        cv.u.x = pk2bf(p0, p1);
        cv.u.y = pk2bf(p2, p3);
        pf[t4] = cv.s4;
      }
      // O += P V and l += P 1  (all on the MFMA pipe)
#pragma unroll
      for (int t4 = 0; t4 < 4; ++t4) {
        oacc[0] = __builtin_amdgcn_mfma_f32_16x16x16bf16_1k(pf[t4], vf[0][t4], oacc[0], 0, 0, 0);
        oacc[1] = __builtin_amdgcn_mfma_f32_16x16x16bf16_1k(pf[t4], vf[1][t4], oacc[1], 0, 0, 0);
        lacc    = __builtin_amdgcn_mfma_f32_16x16x16bf16_1k(pf[t4], vone, lacc, 0, 0, 0);
      }
    }
    // normalization: lacc rows == oacc rows -> per-lane rcp, no shuffles
    f32x4 inv;
#pragma unroll
    for (int r = 0; r < 4; ++r) inv[r] = __builtin_amdgcn_rcpf(lacc[r]);
    outv[0] += oacc[0] * inv;
    outv[1] += oacc[1] * inv;
  }

  // store O (layout [qrow=quad*4+r][dcol=n] per dh tile): scalar bf16
  int b = bh >> 3, h = bh & 7;
#pragma unroll
  for (int dh = 0; dh < 2; ++dh) {
    f32x4 v = outv[dh];
#pragma unroll
    for (int r = 0; r < 4; ++r) {
      size_t row = (size_t)b * 2048 + qbase + quad * 4 + r;
      osum[row * 256 + h * 32 + dh * 16 + n] = f2bf(v[r]);
    }
  }
}

// ------------------------------------------- output projection (MFMA, C^T)
// out[t][c] = sum_k osum[t][k]*Wo[c][k] + 2*bo[c], fp32 out.  xf prefetched.
__global__ __launch_bounds__(256) void outproj_kernel(
    const ushort* __restrict__ osum, const ushort* __restrict__ wo,
    const float* __restrict__ bo, float* __restrict__ out) {
  int tid = threadIdx.x;
  int w = tid >> 6, lane = tid & 63;
  int n = lane & 15, quad = lane >> 4;
  int cbase = blockIdx.y * 128 + w * 32;

  short8 wfrag[2][8];
#pragma unroll
  for (int ct = 0; ct < 2; ++ct)
#pragma unroll
    for (int kc = 0; kc < 8; ++kc)
      wfrag[ct][kc] = *(const short8*)(wo + (size_t)(cbase + ct * 16 + n) * 256 + kc * 32 + quad * 8);
  float4 bt[2];
  bt[0] = *(const float4*)(bo + cbase + quad * 4);
  bt[1] = *(const float4*)(bo + cbase + 16 + quad * 4);

  const ushort* abase = osum + (size_t)(blockIdx.x * 128) * 256;
  short8 xfA[8], xfB[8];
#pragma unroll
  for (int kc = 0; kc < 8; ++kc)
    xfA[kc] = *(const short8*)(abase + (size_t)n * 256 + kc * 32 + quad * 8);

#pragma unroll
  for (int tt = 0; tt < 8; ++tt) {
    const short8* cur = (tt & 1) ? xfB : xfA;
    short8* nxt = (tt & 1) ? xfA : xfB;
    if (tt < 7) {
#pragma unroll
      for (int kc = 0; kc < 8; ++kc)
        nxt[kc] = *(const short8*)(abase + (size_t)((tt + 1) * 16 + n) * 256 + kc * 32 + quad * 8);
    }
    int tok = blockIdx.x * 128 + tt * 16 + n;
    f32x4 acc[2] = {{0.f, 0.f, 0.f, 0.f}, {0.f, 0.f, 0.f, 0.f}};
#pragma unroll
    for (int ct = 0; ct < 2; ++ct)
#pragma unroll
      for (int kc = 0; kc < 8; ++kc)
        acc[ct] = __builtin_amdgcn_mfma_f32_16x16x32_bf16(wfrag[ct][kc], cur[kc], acc[ct], 0, 0, 0);
#pragma unroll
    for (int ct = 0; ct < 2; ++ct) {
      int c = cbase + ct * 16 + quad * 4;
      float* bp = (float*)&bt[ct];
      float4 st;
      st.x = acc[ct][0] + 2.0f * bp[0];
      st.y = acc[ct][1] + 2.0f * bp[1];
      st.z = acc[ct][2] + 2.0f * bp[2];
      st.w = acc[ct][3] + 2.0f * bp[3];
      *(float4*)(out + (size_t)tok * 256 + c) = st;
    }
  }
}

extern "C" void kernel_launch(void* const* d_in, const int* in_sizes, int n_in,
                              void* d_out, int out_size, void* d_ws, size_t ws_size,
                              hipStream_t stream) {
  const float* x   = (const float*)d_in[0];
  const float* lng = (const float*)d_in[1];
  const float* lnb = (const float*)d_in[2];
  const float* Wq  = (const float*)d_in[3];
  const float* bq  = (const float*)d_in[4];
  const float* Wk  = (const float*)d_in[5];
  const float* bk  = (const float*)d_in[6];
  const float* Wv  = (const float*)d_in[7];
  const float* bv  = (const float*)d_in[8];
  const float* Wo  = (const float*)d_in[9];
  const float* bo  = (const float*)d_in[10];
  float* out = (float*)d_out;

  ushort* ws = (ushort*)d_ws;
  const size_t XN  = (size_t)49152 * 256;      // 12,582,912
  const size_t QKV = (size_t)64 * 2048 * 32;   //  4,194,304
  ushort* xn   = ws;
  ushort* wbf  = xn + XN;          // [Wq|Wk|Wv|Wo] x 65536
  ushort* qb   = wbf + 4 * 65536;
  ushort* keb  = qb  + QKV;
  ushort* vTe  = keb + QKV;
  ushort* klb  = vTe + QKV;
  ushort* vTl  = klb + QKV;
  ushort* osum = vTl + QKV;

  hipLaunchKernelGGL(ln_wcast_kernel, dim3(12544), dim3(256), 0, stream,
                     x, lng, lnb, Wq, Wk, Wv, Wo, xn, wbf);
  hipLaunchKernelGGL(proj_kernel, dim3(128, 2, 3), dim3(256), 0, stream,
                     xn, wbf, wbf + 65536, wbf + 131072, bq, bk, bv,
                     qb, keb, vTe, klb, vTl);
  hipLaunchKernelGGL(attn_kernel, dim3(8, 256), dim3(256), 0, stream,
                     qb, keb, vTe, klb, vTl, osum);
  hipLaunchKernelGGL(outproj_kernel, dim3(128, 2), dim3(256), 0, stream,
                     osum, wbf + 196608, bo, out);
}

// Round 5
// 293.932 us; speedup vs baseline: 1.3409x; 1.3409x over previous
//
#include <hip/hip_runtime.h>
#include <hip/hip_bf16.h>
#include <math.h>

#define LN_EPS 1e-5f
// dim^-0.5 * log2(e): folded into q so softmax is exp2(s) with no muls
#define QSCALE 0.09016844005556021f

typedef __attribute__((ext_vector_type(8))) short short8;
typedef __attribute__((ext_vector_type(4))) short short4v;
typedef __attribute__((ext_vector_type(4))) float f32x4;

__device__ inline ushort f2bf(float f) {
  __hip_bfloat16 h = __float2bfloat16(f);
  return *reinterpret_cast<ushort*>(&h);
}

// pack two positive fp32 into bf16 pair (lo=a, hi=b): +0x8000 then v_perm.
// (hardware-verified; do NOT swap for cvt_pk asm)
__device__ inline uint pk2bf(float a, float b) {
  uint ua = __float_as_uint(a) + 0x8000u;
  uint ub = __float_as_uint(b) + 0x8000u;
  return __builtin_amdgcn_perm(ub, ua, 0x07060302u);
}

// Shapes (fixed): b=8, n=2048/stream, 3 streams, dim=256, heads=8, d=32.
// xn (bf16): [8*6144][256].  q/k (bf16): [bh][2048][32].
// vT2 (bf16, FRAGMENT layout): [bh][32 tiles][2 dh][4 t4][64 lane][4] --
//   element = V[key = tile*64 + t4*16 + (lane>>4)*4 + j][d = dh*16 + (lane&15)]
//   i.e. exactly the 16x16x16bf16 B-fragment each attn lane needs.
// osum_e / osum_l (bf16): [b*2048][256] each (per-stream normalized O;
// osum_l aliases the dead xn region -- xn is only read by proj_kernel).

// ---------------------- fused: LN-normalize -> bf16  +  weight cast -> bf16
__global__ __launch_bounds__(256) void ln_wcast_kernel(
    const float* __restrict__ x, const float* __restrict__ lng,
    const float* __restrict__ lnb,
    const float* __restrict__ Wq, const float* __restrict__ Wk,
    const float* __restrict__ Wv, const float* __restrict__ Wo,
    ushort* __restrict__ xn, ushort* __restrict__ wbf) {
  if (blockIdx.x < 256) {
    int t = blockIdx.x * 256 + threadIdx.x;
    int e0 = t * 4;
    int m = e0 >> 16, off = e0 & 65535;
    const float* src = (m == 0) ? Wq : (m == 1) ? Wk : (m == 2) ? Wv : Wo;
    float4 v = *(const float4*)(src + off);
    ushort4 o;
    o.x = f2bf(v.x); o.y = f2bf(v.y); o.z = f2bf(v.z); o.w = f2bf(v.w);
    *(ushort4*)(wbf + m * 65536 + off) = o;
    return;
  }
  int w = threadIdx.x >> 6;
  int lane = threadIdx.x & 63;
  size_t token = (size_t)(blockIdx.x - 256) * 4 + w;
  float4 v = *(const float4*)(x + token * 256 + lane * 4);
  float s  = v.x + v.y + v.z + v.w;
  float s2 = v.x * v.x + v.y * v.y + v.z * v.z + v.w * v.w;
#pragma unroll
  for (int off = 32; off >= 1; off >>= 1) {
    s  += __shfl_xor(s, off, 64);
    s2 += __shfl_xor(s2, off, 64);
  }
  float mu  = s * (1.0f / 256.0f);
  float var = s2 * (1.0f / 256.0f) - mu * mu;
  float rs  = rsqrtf(var + LN_EPS);
  float4 g = *(const float4*)(lng + lane * 4);
  float4 bb = *(const float4*)(lnb + lane * 4);
  ushort4 o;
  o.x = f2bf((v.x - mu) * rs * g.x + bb.x);
  o.y = f2bf((v.y - mu) * rs * g.y + bb.y);
  o.z = f2bf((v.z - mu) * rs * g.z + bb.z);
  o.w = f2bf((v.w - mu) * rs * g.w + bb.w);
  *(ushort4*)(xn + token * 256 + lane * 4) = o;
}

// ------------------------------------------------- QKV projections (MFMA)
// z: 0 = q (stream 0, Wq, scaled, C^T out)
// z: 1 = kv_e, 2 = kv_l: xf loaded ONCE feeds Wk (A-form, C^T) AND Wv
// (B-form, fragment-layout vT2 out).  No LDS; xf double-buffered.
__global__ __launch_bounds__(256) void proj_kernel(
    const ushort* __restrict__ xn,
    const ushort* __restrict__ wq, const ushort* __restrict__ wk,
    const ushort* __restrict__ wv,
    const float* __restrict__ bq, const float* __restrict__ bk,
    const float* __restrict__ bv,
    ushort* __restrict__ qb, ushort* __restrict__ keb, ushort* __restrict__ vTe,
    ushort* __restrict__ klb, ushort* __restrict__ vTl) {
  int z = blockIdx.z;
  int tid = threadIdx.x;
  int w = tid >> 6, lane = tid & 63;
  int n = lane & 15, quad = lane >> 4;
  int cbase = blockIdx.y * 128 + w * 32;
  int b = (blockIdx.x * 128) >> 11;
  int r0 = (blockIdx.x * 128) & 2047;

  if (z == 0) {
    const ushort* xbase = xn + ((size_t)b * 6144 + r0) * 256;
    short8 wf[2][8];
#pragma unroll
    for (int ct = 0; ct < 2; ++ct)
#pragma unroll
      for (int kc = 0; kc < 8; ++kc)
        wf[ct][kc] = *(const short8*)(wq + (size_t)(cbase + ct * 16 + n) * 256 + kc * 32 + quad * 8);
    float4 bt[2];
    bt[0] = *(const float4*)(bq + cbase + quad * 4);
    bt[1] = *(const float4*)(bq + cbase + 16 + quad * 4);

    short8 xfA[8], xfB[8];
#pragma unroll
    for (int kc = 0; kc < 8; ++kc)
      xfA[kc] = *(const short8*)(xbase + (size_t)n * 256 + kc * 32 + quad * 8);

#pragma unroll
    for (int tt = 0; tt < 8; ++tt) {
      const short8* cur = (tt & 1) ? xfB : xfA;
      short8* nxt = (tt & 1) ? xfA : xfB;
      if (tt < 7) {
#pragma unroll
        for (int kc = 0; kc < 8; ++kc)
          nxt[kc] = *(const short8*)(xbase + (size_t)((tt + 1) * 16 + n) * 256 + kc * 32 + quad * 8);
      }
      f32x4 acc[2] = {{0.f, 0.f, 0.f, 0.f}, {0.f, 0.f, 0.f, 0.f}};
#pragma unroll
      for (int ct = 0; ct < 2; ++ct)
#pragma unroll
        for (int kc = 0; kc < 8; ++kc)
          acc[ct] = __builtin_amdgcn_mfma_f32_16x16x32_bf16(wf[ct][kc], cur[kc], acc[ct], 0, 0, 0);
      int n2 = r0 + tt * 16 + n;
#pragma unroll
      for (int ct = 0; ct < 2; ++ct) {
        int c = cbase + ct * 16 + quad * 4;
        int h = c >> 5, d = c & 31;
        float* bp = (float*)&bt[ct];
        ushort4 st;
        st.x = f2bf((acc[ct][0] + bp[0]) * QSCALE);
        st.y = f2bf((acc[ct][1] + bp[1]) * QSCALE);
        st.z = f2bf((acc[ct][2] + bp[2]) * QSCALE);
        st.w = f2bf((acc[ct][3] + bp[3]) * QSCALE);
        *(ushort4*)(qb + (((size_t)(b * 8 + h) * 2048) + n2) * 32 + d) = st;
      }
    }
  } else {
    int s = z;
    ushort* kout = (z == 1) ? keb : klb;
    ushort* vout = (z == 1) ? vTe : vTl;
    const ushort* xbase = xn + ((size_t)b * 6144 + s * 2048 + r0) * 256;
    short8 wfk[2][8], wfv[2][8];
#pragma unroll
    for (int ct = 0; ct < 2; ++ct)
#pragma unroll
      for (int kc = 0; kc < 8; ++kc) {
        wfk[ct][kc] = *(const short8*)(wk + (size_t)(cbase + ct * 16 + n) * 256 + kc * 32 + quad * 8);
        wfv[ct][kc] = *(const short8*)(wv + (size_t)(cbase + ct * 16 + n) * 256 + kc * 32 + quad * 8);
      }
    float4 btk[2];
    btk[0] = *(const float4*)(bk + cbase + quad * 4);
    btk[1] = *(const float4*)(bk + cbase + 16 + quad * 4);
    float bsv[2] = {bv[cbase + n], bv[cbase + 16 + n]};

    short8 xfA[8], xfB[8];
#pragma unroll
    for (int kc = 0; kc < 8; ++kc)
      xfA[kc] = *(const short8*)(xbase + (size_t)n * 256 + kc * 32 + quad * 8);

#pragma unroll
    for (int tt = 0; tt < 8; ++tt) {
      const short8* cur = (tt & 1) ? xfB : xfA;
      short8* nxt = (tt & 1) ? xfA : xfB;
      if (tt < 7) {
#pragma unroll
        for (int kc = 0; kc < 8; ++kc)
          nxt[kc] = *(const short8*)(xbase + (size_t)((tt + 1) * 16 + n) * 256 + kc * 32 + quad * 8);
      }
      f32x4 ack[2] = {{0.f, 0.f, 0.f, 0.f}, {0.f, 0.f, 0.f, 0.f}};
      f32x4 acv[2] = {{0.f, 0.f, 0.f, 0.f}, {0.f, 0.f, 0.f, 0.f}};
#pragma unroll
      for (int ct = 0; ct < 2; ++ct)
#pragma unroll
        for (int kc = 0; kc < 8; ++kc) {
          ack[ct] = __builtin_amdgcn_mfma_f32_16x16x32_bf16(wfk[ct][kc], cur[kc], ack[ct], 0, 0, 0);
          acv[ct] = __builtin_amdgcn_mfma_f32_16x16x32_bf16(cur[kc], wfv[ct][kc], acv[ct], 0, 0, 0);
        }
      // store k: C^T  (lane: token n2, cols quad*4+r)
      int n2 = r0 + tt * 16 + n;
#pragma unroll
      for (int ct = 0; ct < 2; ++ct) {
        int c = cbase + ct * 16 + quad * 4;
        int h = c >> 5, d = c & 31;
        float* bp = (float*)&btk[ct];
        ushort4 st;
        st.x = f2bf(ack[ct][0] + bp[0]);
        st.y = f2bf(ack[ct][1] + bp[1]);
        st.z = f2bf(ack[ct][2] + bp[2]);
        st.w = f2bf(ack[ct][3] + bp[3]);
        *(ushort4*)(kout + (((size_t)(b * 8 + h) * 2048) + n2) * 32 + d) = st;
      }
      // store v: B-fragment layout vT2[bh][tile][dh][t4][lane'][j]
      int tq = r0 + tt * 16 + quad * 4;
      int tile = tq >> 6;
      int t4 = (tq >> 4) & 3;
      int qp = (tq >> 2) & 3;  // quad' of the consuming attn lane
#pragma unroll
      for (int ct = 0; ct < 2; ++ct) {
        int c = cbase + ct * 16 + n;
        int h = c >> 5, d = c & 31;
        int dh = d >> 4, np = d & 15;
        ushort4 st;
        st.x = f2bf(acv[ct][0] + bsv[ct]);
        st.y = f2bf(acv[ct][1] + bsv[ct]);
        st.z = f2bf(acv[ct][2] + bsv[ct]);
        st.w = f2bf(acv[ct][3] + bsv[ct]);
        *(ushort4*)(vout + (size_t)(b * 8 + h) * 65536
                    + (size_t)((((tile * 2 + dh) * 4 + t4) * 64 + qp * 16 + np) * 4)) = st;
      }
    }
  }
}

// ------------------------------------------------ flash attention bf16 MFMA
// Round-4 post-mortem: dropping the K/V prefetch made each jt a serial
// load->QK->exp->PV chain; occupancy 2x couldn't compensate (MfmaUtil 22).
// This version keeps the round-3 ILP (one-tile-ahead prefetch, now an
// explicit ping-pong: no reg copies) AND gets 2x block supply by splitting
// the two kv-streams across blocks (grid 2048, 32 jt per wave, gq=2).
// Per-stream O is normalized and stored separately (osum_e / osum_l);
// outproj sums the streams.  V consumed directly from global in B-fragment
// layout (no LDS).  Swizzle: all 16 q-chunks of one (bh,s) on one XCD.
__global__ __launch_bounds__(256, 4) void attn_kernel(
    const ushort* __restrict__ q,
    const ushort* __restrict__ ke, const ushort* __restrict__ vTe,
    const ushort* __restrict__ kl, const ushort* __restrict__ vTl,
    ushort* __restrict__ osum_e, ushort* __restrict__ osum_l) {
  int tid = threadIdx.x;
  int w = tid >> 6, lane = tid & 63;
  int n = lane & 15, quad = lane >> 4;

  union { uint2 u; short4v s; } one_u;
  one_u.u.x = 0x3F803F80u; one_u.u.y = 0x3F803F80u;  // bf16 1.0 x4
  const short4v vone = one_u.s;

  // L -> (xcd, idx): per XCD, blocks ordered bh-major then stream then q0
  int L = blockIdx.y * 8 + blockIdx.x;
  int xcd = L & 7, idx = L >> 3;          // idx in [0,256)
  int bh = (idx >> 5) * 8 + xcd;          // h = xcd; b = idx>>5
  int rem = idx & 31;
  int s = rem >> 4;                        // stream 0=e, 1=l
  int q0 = (rem & 15) * 128;
  int qbase = q0 + w * 32;

  const ushort* K  = (s == 0 ? ke : kl) + (size_t)bh * 2048 * 32;
  const ushort* VT = (s == 0 ? vTe : vTl) + (size_t)bh * 65536;
  ushort* osum = (s == 0) ? osum_e : osum_l;

  short8 qfrag[2];
#pragma unroll
  for (int gq = 0; gq < 2; ++gq)
    qfrag[gq] = *(const short8*)(q + ((size_t)bh * 2048 + qbase + gq * 16 + n) * 32 + quad * 8);

  f32x4 lacc[2];
  f32x4 oacc[2][2];
#pragma unroll
  for (int gq = 0; gq < 2; ++gq) {
    lacc[gq] = (f32x4){0.f, 0.f, 0.f, 0.f};
#pragma unroll
    for (int dh = 0; dh < 2; ++dh) oacc[gq][dh] = (f32x4){0.f, 0.f, 0.f, 0.f};
  }

  auto loadKV = [&](short8* kf, short4v (*vf)[4], int jt) {
    size_t tb = (size_t)jt * 2048;
#pragma unroll
    for (int t4 = 0; t4 < 4; ++t4)
      kf[t4] = *(const short8*)(K + tb + (size_t)(t4 * 16 + n) * 32 + quad * 8);
#pragma unroll
    for (int dh = 0; dh < 2; ++dh)
#pragma unroll
      for (int t4 = 0; t4 < 4; ++t4)
        vf[dh][t4] = *(const short4v*)(VT + tb + (dh * 4 + t4) * 256 + lane * 4);
  };

  auto compute = [&](const short8* kf, const short4v (*vf)[4]) {
#pragma unroll
    for (int gq = 0; gq < 2; ++gq) {
      // S^T tiles (16 keys x 16 qrows), K=32 = full head dim
      f32x4 sacc[4];
#pragma unroll
      for (int t4 = 0; t4 < 4; ++t4) {
        f32x4 z = {0.f, 0.f, 0.f, 0.f};
        sacc[t4] = __builtin_amdgcn_mfma_f32_16x16x32_bf16(kf[t4], qfrag[gq], z, 0, 0, 0);
      }
      // p = exp2(s), pack to bf16 A-fragments in-register
      short4v pf[4];
#pragma unroll
      for (int t4 = 0; t4 < 4; ++t4) {
        float p0 = __builtin_amdgcn_exp2f(sacc[t4][0]);
        float p1 = __builtin_amdgcn_exp2f(sacc[t4][1]);
        float p2 = __builtin_amdgcn_exp2f(sacc[t4][2]);
        float p3 = __builtin_amdgcn_exp2f(sacc[t4][3]);
        union { uint2 u; short4v s4; } cv;
        cv.u.x = pk2bf(p0, p1);
        cv.u.y = pk2bf(p2, p3);
        pf[t4] = cv.s4;
      }
      // O += P V and l += P 1  (all on the MFMA pipe)
#pragma unroll
      for (int t4 = 0; t4 < 4; ++t4) {
        oacc[gq][0] = __builtin_amdgcn_mfma_f32_16x16x16bf16_1k(pf[t4], vf[0][t4], oacc[gq][0], 0, 0, 0);
        oacc[gq][1] = __builtin_amdgcn_mfma_f32_16x16x16bf16_1k(pf[t4], vf[1][t4], oacc[gq][1], 0, 0, 0);
        lacc[gq]    = __builtin_amdgcn_mfma_f32_16x16x16bf16_1k(pf[t4], vone, lacc[gq], 0, 0, 0);
      }
    }
  };

  short8 kfA[4], kfB[4];
  short4v vfA[2][4], vfB[2][4];
  loadKV(kfA, vfA, 0);
  for (int jt = 0; jt < 32; jt += 2) {
    loadKV(kfB, vfB, jt + 1);   // in flight during compute(A)
    compute(kfA, vfA);
    if (jt + 2 < 32) loadKV(kfA, vfA, jt + 2);
    compute(kfB, vfB);
  }

  // normalization: lacc rows == oacc rows -> per-lane rcp, no shuffles
  int b = bh >> 3, h = bh & 7;
#pragma unroll
  for (int gq = 0; gq < 2; ++gq) {
    f32x4 inv;
#pragma unroll
    for (int r = 0; r < 4; ++r) inv[r] = __builtin_amdgcn_rcpf(lacc[gq][r]);
#pragma unroll
    for (int dh = 0; dh < 2; ++dh) {
      f32x4 v = oacc[gq][dh] * inv;
#pragma unroll
      for (int r = 0; r < 4; ++r) {
        size_t row = (size_t)b * 2048 + qbase + gq * 16 + quad * 4 + r;
        osum[row * 256 + h * 32 + dh * 16 + n] = f2bf(v[r]);
      }
    }
  }
}

// ------------------------------------------- output projection (MFMA, C^T)
// out[t][c] = sum_k (ose[t][k]+osl[t][k])*Wo[c][k] + 2*bo[c]: both streams
// accumulated into the same MFMA C (K=512 total).  64-row blocks (grid 512).
__global__ __launch_bounds__(256) void outproj_kernel(
    const ushort* __restrict__ ose, const ushort* __restrict__ osl,
    const ushort* __restrict__ wo,
    const float* __restrict__ bo, float* __restrict__ out) {
  int tid = threadIdx.x;
  int w = tid >> 6, lane = tid & 63;
  int n = lane & 15, quad = lane >> 4;
  int cbase = blockIdx.y * 128 + w * 32;

  short8 wfrag[2][8];
#pragma unroll
  for (int ct = 0; ct < 2; ++ct)
#pragma unroll
    for (int kc = 0; kc < 8; ++kc)
      wfrag[ct][kc] = *(const short8*)(wo + (size_t)(cbase + ct * 16 + n) * 256 + kc * 32 + quad * 8);
  float4 bt[2];
  bt[0] = *(const float4*)(bo + cbase + quad * 4);
  bt[1] = *(const float4*)(bo + cbase + 16 + quad * 4);

  const ushort* ae = ose + (size_t)(blockIdx.x * 64) * 256;
  const ushort* al = osl + (size_t)(blockIdx.x * 64) * 256;

#pragma unroll
  for (int tt = 0; tt < 4; ++tt) {
    short8 xe[8], xl[8];
#pragma unroll
    for (int kc = 0; kc < 8; ++kc)
      xe[kc] = *(const short8*)(ae + (size_t)(tt * 16 + n) * 256 + kc * 32 + quad * 8);
#pragma unroll
    for (int kc = 0; kc < 8; ++kc)
      xl[kc] = *(const short8*)(al + (size_t)(tt * 16 + n) * 256 + kc * 32 + quad * 8);

    int tok = blockIdx.x * 64 + tt * 16 + n;
    f32x4 acc[2] = {{0.f, 0.f, 0.f, 0.f}, {0.f, 0.f, 0.f, 0.f}};
#pragma unroll
    for (int ct = 0; ct < 2; ++ct)
#pragma unroll
      for (int kc = 0; kc < 8; ++kc)
        acc[ct] = __builtin_amdgcn_mfma_f32_16x16x32_bf16(wfrag[ct][kc], xe[kc], acc[ct], 0, 0, 0);
#pragma unroll
    for (int ct = 0; ct < 2; ++ct)
#pragma unroll
      for (int kc = 0; kc < 8; ++kc)
        acc[ct] = __builtin_amdgcn_mfma_f32_16x16x32_bf16(wfrag[ct][kc], xl[kc], acc[ct], 0, 0, 0);
#pragma unroll
    for (int ct = 0; ct < 2; ++ct) {
      int c = cbase + ct * 16 + quad * 4;
      float* bp = (float*)&bt[ct];
      float4 st;
      st.x = acc[ct][0] + 2.0f * bp[0];
      st.y = acc[ct][1] + 2.0f * bp[1];
      st.z = acc[ct][2] + 2.0f * bp[2];
      st.w = acc[ct][3] + 2.0f * bp[3];
      *(float4*)(out + (size_t)tok * 256 + c) = st;
    }
  }
}

extern "C" void kernel_launch(void* const* d_in, const int* in_sizes, int n_in,
                              void* d_out, int out_size, void* d_ws, size_t ws_size,
                              hipStream_t stream) {
  const float* x   = (const float*)d_in[0];
  const float* lng = (const float*)d_in[1];
  const float* lnb = (const float*)d_in[2];
  const float* Wq  = (const float*)d_in[3];
  const float* bq  = (const float*)d_in[4];
  const float* Wk  = (const float*)d_in[5];
  const float* bk  = (const float*)d_in[6];
  const float* Wv  = (const float*)d_in[7];
  const float* bv  = (const float*)d_in[8];
  const float* Wo  = (const float*)d_in[9];
  const float* bo  = (const float*)d_in[10];
  float* out = (float*)d_out;

  ushort* ws = (ushort*)d_ws;
  const size_t XN  = (size_t)49152 * 256;      // 12,582,912
  const size_t QKV = (size_t)64 * 2048 * 32;   //  4,194,304
  ushort* xn     = ws;
  ushort* wbf    = xn + XN;          // [Wq|Wk|Wv|Wo] x 65536
  ushort* qb     = wbf + 4 * 65536;
  ushort* keb    = qb  + QKV;
  ushort* vTe    = keb + QKV;
  ushort* klb    = vTe + QKV;
  ushort* vTl    = klb + QKV;
  ushort* osum_e = vTl + QKV;
  ushort* osum_l = xn;               // alias: xn is dead after proj_kernel

  hipLaunchKernelGGL(ln_wcast_kernel, dim3(12544), dim3(256), 0, stream,
                     x, lng, lnb, Wq, Wk, Wv, Wo, xn, wbf);
  hipLaunchKernelGGL(proj_kernel, dim3(128, 2, 3), dim3(256), 0, stream,
                     xn, wbf, wbf + 65536, wbf + 131072, bq, bk, bv,
                     qb, keb, vTe, klb, vTl);
  hipLaunchKernelGGL(attn_kernel, dim3(8, 256), dim3(256), 0, stream,
                     qb, keb, vTe, klb, vTl, osum_e, osum_l);
  hipLaunchKernelGGL(outproj_kernel, dim3(256, 2), dim3(256), 0, stream,
                     osum_e, osum_l, wbf + 196608, bo, out);
}

// Round 6
// 271.597 us; speedup vs baseline: 1.4511x; 1.0822x over previous
//
#include <hip/hip_runtime.h>
#include <hip/hip_bf16.h>
#include <math.h>

#define LN_EPS 1e-5f
// dim^-0.5 * log2(e): folded into q so softmax is exp2(s) with no muls
#define QSCALE 0.09016844005556021f

typedef __attribute__((ext_vector_type(8))) short short8;
typedef __attribute__((ext_vector_type(4))) short short4v;
typedef __attribute__((ext_vector_type(4))) float f32x4;
typedef __attribute__((ext_vector_type(16))) float f32x16;

__device__ inline ushort f2bf(float f) {
  __hip_bfloat16 h = __float2bfloat16(f);
  return *reinterpret_cast<ushort*>(&h);
}

// pack two positive fp32 into bf16 pair (lo=a, hi=b): +0x8000 then v_perm.
// (hardware-verified; do NOT swap for cvt_pk asm)
__device__ inline uint pk2bf(float a, float b) {
  uint ua = __float_as_uint(a) + 0x8000u;
  uint ub = __float_as_uint(b) + 0x8000u;
  return __builtin_amdgcn_perm(ub, ua, 0x07060302u);
}

// Shapes (fixed): b=8, n=2048/stream, 3 streams, dim=256, heads=8, d=32.
// xn (bf16): [8*6144][256].  q/k (bf16): [bh][2048][32] row-major -- these
//   double as 32x32x16 MFMA A/B fragment sources (row=lane&31, k=hi*8+i ->
//   8 consecutive bf16 at d = slice*16 + hi*8).
// vT3 (bf16, 32x32 B-FRAGMENT layout): [bh][64 ktile32][2 u][64 lane][8]:
//   elem = V[key = ktile*32 + 16u + (i&3) + 8*(i>>2) + 4*(lane>>5)]
//            [d = lane&31]
//   This key permutation equals the 32x32 MFMA C-row pattern, so attn's
//   P-register file (S^T C-layout) feeds PV's A operand with NO data
//   movement, and V loads are fully-coalesced lane*8 short8s.
// osum_e / osum_l (bf16): [b*2048][256] (osum_l aliases dead xn region).

// ---------------------- fused: LN-normalize -> bf16  +  weight cast -> bf16
__global__ __launch_bounds__(256) void ln_wcast_kernel(
    const float* __restrict__ x, const float* __restrict__ lng,
    const float* __restrict__ lnb,
    const float* __restrict__ Wq, const float* __restrict__ Wk,
    const float* __restrict__ Wv, const float* __restrict__ Wo,
    ushort* __restrict__ xn, ushort* __restrict__ wbf) {
  if (blockIdx.x < 256) {
    int t = blockIdx.x * 256 + threadIdx.x;
    int e0 = t * 4;
    int m = e0 >> 16, off = e0 & 65535;
    const float* src = (m == 0) ? Wq : (m == 1) ? Wk : (m == 2) ? Wv : Wo;
    float4 v = *(const float4*)(src + off);
    ushort4 o;
    o.x = f2bf(v.x); o.y = f2bf(v.y); o.z = f2bf(v.z); o.w = f2bf(v.w);
    *(ushort4*)(wbf + m * 65536 + off) = o;
    return;
  }
  int w = threadIdx.x >> 6;
  int lane = threadIdx.x & 63;
  size_t token = (size_t)(blockIdx.x - 256) * 4 + w;
  float4 v = *(const float4*)(x + token * 256 + lane * 4);
  float s  = v.x + v.y + v.z + v.w;
  float s2 = v.x * v.x + v.y * v.y + v.z * v.z + v.w * v.w;
#pragma unroll
  for (int off = 32; off >= 1; off >>= 1) {
    s  += __shfl_xor(s, off, 64);
    s2 += __shfl_xor(s2, off, 64);
  }
  float mu  = s * (1.0f / 256.0f);
  float var = s2 * (1.0f / 256.0f) - mu * mu;
  float rs  = rsqrtf(var + LN_EPS);
  float4 g = *(const float4*)(lng + lane * 4);
  float4 bb = *(const float4*)(lnb + lane * 4);
  ushort4 o;
  o.x = f2bf((v.x - mu) * rs * g.x + bb.x);
  o.y = f2bf((v.y - mu) * rs * g.y + bb.y);
  o.z = f2bf((v.z - mu) * rs * g.z + bb.z);
  o.w = f2bf((v.w - mu) * rs * g.w + bb.w);
  *(ushort4*)(xn + token * 256 + lane * 4) = o;
}

// ------------------------------------------------- QKV projections (MFMA)
// z: 0 = q (stream 0, Wq, scaled, C^T out)
// z: 1 = kv_e, 2 = kv_l: xf loaded ONCE feeds Wk (A-form, C^T) AND Wv
// (B-form, 32x32-fragment vT3 out).  No LDS; xf double-buffered.
__global__ __launch_bounds__(256) void proj_kernel(
    const ushort* __restrict__ xn,
    const ushort* __restrict__ wq, const ushort* __restrict__ wk,
    const ushort* __restrict__ wv,
    const float* __restrict__ bq, const float* __restrict__ bk,
    const float* __restrict__ bv,
    ushort* __restrict__ qb, ushort* __restrict__ keb, ushort* __restrict__ vTe,
    ushort* __restrict__ klb, ushort* __restrict__ vTl) {
  int z = blockIdx.z;
  int tid = threadIdx.x;
  int w = tid >> 6, lane = tid & 63;
  int n = lane & 15, quad = lane >> 4;
  int cbase = blockIdx.y * 128 + w * 32;
  int b = (blockIdx.x * 128) >> 11;
  int r0 = (blockIdx.x * 128) & 2047;

  if (z == 0) {
    const ushort* xbase = xn + ((size_t)b * 6144 + r0) * 256;
    short8 wf[2][8];
#pragma unroll
    for (int ct = 0; ct < 2; ++ct)
#pragma unroll
      for (int kc = 0; kc < 8; ++kc)
        wf[ct][kc] = *(const short8*)(wq + (size_t)(cbase + ct * 16 + n) * 256 + kc * 32 + quad * 8);
    float4 bt[2];
    bt[0] = *(const float4*)(bq + cbase + quad * 4);
    bt[1] = *(const float4*)(bq + cbase + 16 + quad * 4);

    short8 xfA[8], xfB[8];
#pragma unroll
    for (int kc = 0; kc < 8; ++kc)
      xfA[kc] = *(const short8*)(xbase + (size_t)n * 256 + kc * 32 + quad * 8);

#pragma unroll
    for (int tt = 0; tt < 8; ++tt) {
      const short8* cur = (tt & 1) ? xfB : xfA;
      short8* nxt = (tt & 1) ? xfA : xfB;
      if (tt < 7) {
#pragma unroll
        for (int kc = 0; kc < 8; ++kc)
          nxt[kc] = *(const short8*)(xbase + (size_t)((tt + 1) * 16 + n) * 256 + kc * 32 + quad * 8);
      }
      f32x4 acc[2] = {{0.f, 0.f, 0.f, 0.f}, {0.f, 0.f, 0.f, 0.f}};
#pragma unroll
      for (int ct = 0; ct < 2; ++ct)
#pragma unroll
        for (int kc = 0; kc < 8; ++kc)
          acc[ct] = __builtin_amdgcn_mfma_f32_16x16x32_bf16(wf[ct][kc], cur[kc], acc[ct], 0, 0, 0);
      int n2 = r0 + tt * 16 + n;
#pragma unroll
      for (int ct = 0; ct < 2; ++ct) {
        int c = cbase + ct * 16 + quad * 4;
        int h = c >> 5, d = c & 31;
        float* bp = (float*)&bt[ct];
        ushort4 st;
        st.x = f2bf((acc[ct][0] + bp[0]) * QSCALE);
        st.y = f2bf((acc[ct][1] + bp[1]) * QSCALE);
        st.z = f2bf((acc[ct][2] + bp[2]) * QSCALE);
        st.w = f2bf((acc[ct][3] + bp[3]) * QSCALE);
        *(ushort4*)(qb + (((size_t)(b * 8 + h) * 2048) + n2) * 32 + d) = st;
      }
    }
  } else {
    int s = z;
    ushort* kout = (z == 1) ? keb : klb;
    ushort* vout = (z == 1) ? vTe : vTl;
    const ushort* xbase = xn + ((size_t)b * 6144 + s * 2048 + r0) * 256;
    short8 wfk[2][8], wfv[2][8];
#pragma unroll
    for (int ct = 0; ct < 2; ++ct)
#pragma unroll
      for (int kc = 0; kc < 8; ++kc) {
        wfk[ct][kc] = *(const short8*)(wk + (size_t)(cbase + ct * 16 + n) * 256 + kc * 32 + quad * 8);
        wfv[ct][kc] = *(const short8*)(wv + (size_t)(cbase + ct * 16 + n) * 256 + kc * 32 + quad * 8);
      }
    float4 btk[2];
    btk[0] = *(const float4*)(bk + cbase + quad * 4);
    btk[1] = *(const float4*)(bk + cbase + 16 + quad * 4);
    float bsv[2] = {bv[cbase + n], bv[cbase + 16 + n]};

    short8 xfA[8], xfB[8];
#pragma unroll
    for (int kc = 0; kc < 8; ++kc)
      xfA[kc] = *(const short8*)(xbase + (size_t)n * 256 + kc * 32 + quad * 8);

#pragma unroll
    for (int tt = 0; tt < 8; ++tt) {
      const short8* cur = (tt & 1) ? xfB : xfA;
      short8* nxt = (tt & 1) ? xfA : xfB;
      if (tt < 7) {
#pragma unroll
        for (int kc = 0; kc < 8; ++kc)
          nxt[kc] = *(const short8*)(xbase + (size_t)((tt + 1) * 16 + n) * 256 + kc * 32 + quad * 8);
      }
      f32x4 ack[2] = {{0.f, 0.f, 0.f, 0.f}, {0.f, 0.f, 0.f, 0.f}};
      f32x4 acv[2] = {{0.f, 0.f, 0.f, 0.f}, {0.f, 0.f, 0.f, 0.f}};
#pragma unroll
      for (int ct = 0; ct < 2; ++ct)
#pragma unroll
        for (int kc = 0; kc < 8; ++kc) {
          ack[ct] = __builtin_amdgcn_mfma_f32_16x16x32_bf16(wfk[ct][kc], cur[kc], ack[ct], 0, 0, 0);
          acv[ct] = __builtin_amdgcn_mfma_f32_16x16x32_bf16(cur[kc], wfv[ct][kc], acv[ct], 0, 0, 0);
        }
      // store k: C^T row-major [bh][2048][32] (lane: token n2, cols quad*4+r)
      int n2 = r0 + tt * 16 + n;
#pragma unroll
      for (int ct = 0; ct < 2; ++ct) {
        int c = cbase + ct * 16 + quad * 4;
        int h = c >> 5, d = c & 31;
        float* bp = (float*)&btk[ct];
        ushort4 st;
        st.x = f2bf(ack[ct][0] + bp[0]);
        st.y = f2bf(ack[ct][1] + bp[1]);
        st.z = f2bf(ack[ct][2] + bp[2]);
        st.w = f2bf(ack[ct][3] + bp[3]);
        *(ushort4*)(kout + (((size_t)(b * 8 + h) * 2048) + n2) * 32 + d) = st;
      }
      // store v: 32x32 B-fragment layout vT3[bh][ktile][u][lane2][8].
      // acv reg r is token tq+r; kappa = quad*4+r -> hi2=quad&1,
      // i = r + 4*(quad>>1)  (verified: 8*(quad>>1)+4*(quad&1) == 4*quad)
      int tq = r0 + tt * 16 + quad * 4;
      int ktile = tq >> 5;
      int u = (tq >> 4) & 1;
      int i0 = 4 * (quad >> 1);
      int hi2 = quad & 1;
#pragma unroll
      for (int ct = 0; ct < 2; ++ct) {
        int c = cbase + ct * 16 + n;
        int h = c >> 5;
        int d = ct * 16 + n;          // c & 31 (cbase is 32-aligned)
        int lane2 = d + 32 * hi2;
        ushort4 st;
        st.x = f2bf(acv[ct][0] + bsv[ct]);
        st.y = f2bf(acv[ct][1] + bsv[ct]);
        st.z = f2bf(acv[ct][2] + bsv[ct]);
        st.w = f2bf(acv[ct][3] + bsv[ct]);
        *(ushort4*)(vout + (size_t)(b * 8 + h) * 65536
                    + ktile * 1024 + u * 512 + lane2 * 8 + i0) = st;
      }
    }
  }
}

// ------------------------------------------------ flash attention bf16 MFMA
// 32x32x16 restructure (round-5 post-mortem: MFMA pipe 59us of 143 was
// half-wasted on K=16 _1k ops; VALU 71us).  Wave owns 32 q-rows; per jt
// (64 keys): QK = 4x 32x32x16, PV = 4x 32x32x16 (vs 32 issues of 16x16
// before).  P stays in registers: S^T C-layout == PV A-layout lane-for-lane;
// the C row permutation is absorbed into vT3's key order.  Denominator on
// VALU (per-lane f32 sums; lane == one q-col), realigned to oacc's q-rows
// once at the end via 16 bpermutes.  Ping-pong K/V prefetch (round 4 proved
// it load-bearing); stream-split grid 2048; setprio around MFMA pairs.
__global__ __launch_bounds__(256, 3) void attn_kernel(
    const ushort* __restrict__ q,
    const ushort* __restrict__ ke, const ushort* __restrict__ vTe,
    const ushort* __restrict__ kl, const ushort* __restrict__ vTl,
    ushort* __restrict__ osum_e, ushort* __restrict__ osum_l) {
  int tid = threadIdx.x;
  int w = tid >> 6, lane = tid & 63;
  int l31 = lane & 31, hi = lane >> 5;

  // L -> (xcd, idx): per XCD, blocks ordered bh-major then stream then q0
  int L = blockIdx.y * 8 + blockIdx.x;
  int xcd = L & 7, idx = L >> 3;          // idx in [0,256)
  int bh = (idx >> 5) * 8 + xcd;
  int rem = idx & 31;
  int s = rem >> 4;                        // stream 0=e, 1=l
  int q0 = (rem & 15) * 128;
  int qbase = q0 + w * 32;

  const ushort* K  = (s == 0 ? ke : kl) + (size_t)bh * 65536;
  const ushort* VT = (s == 0 ? vTe : vTl) + (size_t)bh * 65536;
  ushort* osum = (s == 0) ? osum_e : osum_l;

  // Q as 32x32x16 B-fragments: col=q=l31, k=hi*8+i, slice sl covers d 16sl..
  short8 qf[2];
#pragma unroll
  for (int sl = 0; sl < 2; ++sl)
    qf[sl] = *(const short8*)(q + ((size_t)bh * 2048 + qbase + l31) * 32 + sl * 16 + hi * 8);

  f32x16 oacc;
#pragma unroll
  for (int r = 0; r < 16; ++r) oacc[r] = 0.f;
  float lsum = 0.f;

  auto loadKV = [&](short8* kf, short8* vf, int jt) {
    const ushort* kb = K + (size_t)jt * 2048;   // 64 keys * 32 d
#pragma unroll
    for (int kt = 0; kt < 2; ++kt)
#pragma unroll
      for (int sl = 0; sl < 2; ++sl)
        kf[kt * 2 + sl] = *(const short8*)(kb + (kt * 32 + l31) * 32 + sl * 16 + hi * 8);
    const ushort* vb = VT + (size_t)jt * 2048 + lane * 8;
#pragma unroll
    for (int m = 0; m < 4; ++m)                 // m = kt*2+u
      vf[m] = *(const short8*)(vb + m * 512);
  };

  auto compute = [&](const short8* kf, const short8* vf) {
#pragma unroll
    for (int kt = 0; kt < 2; ++kt) {
      f32x16 sacc;
#pragma unroll
      for (int r = 0; r < 16; ++r) sacc[r] = 0.f;
      __builtin_amdgcn_s_setprio(1);
      sacc = __builtin_amdgcn_mfma_f32_32x32x16_bf16(kf[kt * 2 + 0], qf[0], sacc, 0, 0, 0);
      sacc = __builtin_amdgcn_mfma_f32_32x32x16_bf16(kf[kt * 2 + 1], qf[1], sacc, 0, 0, 0);
      __builtin_amdgcn_s_setprio(0);
      // p = exp2(s); per-lane f32 denominator partial (lane = one q-col)
      float p[16];
#pragma unroll
      for (int r = 0; r < 16; ++r) p[r] = __builtin_amdgcn_exp2f(sacc[r]);
      float ps = 0.f;
#pragma unroll
      for (int r = 0; r < 16; ++r) ps += p[r];
      lsum += ps;
      // pack C regs [8u..8u+7] -> PV A-fragment for issue u (key perm is
      // baked into vT3's layout)
      short8 pa[2];
#pragma unroll
      for (int u = 0; u < 2; ++u) {
        union { uint4 uu; short8 s8; } cv;
        cv.uu.x = pk2bf(p[8 * u + 0], p[8 * u + 1]);
        cv.uu.y = pk2bf(p[8 * u + 2], p[8 * u + 3]);
        cv.uu.z = pk2bf(p[8 * u + 4], p[8 * u + 5]);
        cv.uu.w = pk2bf(p[8 * u + 6], p[8 * u + 7]);
        pa[u] = cv.s8;
      }
      __builtin_amdgcn_s_setprio(1);
      oacc = __builtin_amdgcn_mfma_f32_32x32x16_bf16(pa[0], vf[kt * 2 + 0], oacc, 0, 0, 0);
      oacc = __builtin_amdgcn_mfma_f32_32x32x16_bf16(pa[1], vf[kt * 2 + 1], oacc, 0, 0, 0);
      __builtin_amdgcn_s_setprio(0);
    }
  };

  short8 kfA[4], kfB[4], vfA[4], vfB[4];
  loadKV(kfA, vfA, 0);
  for (int jt = 0; jt < 32; jt += 2) {
    loadKV(kfB, vfB, jt + 1);   // in flight during compute(A)
    compute(kfA, vfA);
    if (jt + 2 < 32) loadKV(kfA, vfA, jt + 2);
    compute(kfB, vfB);
  }

  // denominator: lanes l and l^32 hold complementary key-halves of q=l31
  lsum += __shfl_xor(lsum, 32, 64);
  float inv = __builtin_amdgcn_rcpf(lsum);

  // oacc reg r is q-row qr=(r&3)+8*(r>>2)+4*hi, col d=l31: fetch inv from
  // lane qr (1 bpermute per reg, once per kernel), normalize, store.
  int b = bh >> 3, h = bh & 7;
#pragma unroll
  for (int r = 0; r < 16; ++r) {
    int qr = (r & 3) + 8 * (r >> 2) + 4 * hi;
    float invr = __shfl(inv, qr, 64);
    float v = oacc[r] * invr;
    size_t row = (size_t)b * 2048 + qbase + qr;
    osum[row * 256 + h * 32 + l31] = f2bf(v);
  }
}

// ------------------------------------------- output projection (MFMA, C^T)
// out[t][c] = sum_k (ose[t][k]+osl[t][k])*Wo[c][k] + 2*bo[c]: both streams
// accumulated into the same MFMA C (K=512 total).  64-row blocks (grid 512).
__global__ __launch_bounds__(256) void outproj_kernel(
    const ushort* __restrict__ ose, const ushort* __restrict__ osl,
    const ushort* __restrict__ wo,
    const float* __restrict__ bo, float* __restrict__ out) {
  int tid = threadIdx.x;
  int w = tid >> 6, lane = tid & 63;
  int n = lane & 15, quad = lane >> 4;
  int cbase = blockIdx.y * 128 + w * 32;

  short8 wfrag[2][8];
#pragma unroll
  for (int ct = 0; ct < 2; ++ct)
#pragma unroll
    for (int kc = 0; kc < 8; ++kc)
      wfrag[ct][kc] = *(const short8*)(wo + (size_t)(cbase + ct * 16 + n) * 256 + kc * 32 + quad * 8);
  float4 bt[2];
  bt[0] = *(const float4*)(bo + cbase + quad * 4);
  bt[1] = *(const float4*)(bo + cbase + 16 + quad * 4);

  const ushort* ae = ose + (size_t)(blockIdx.x * 64) * 256;
  const ushort* al = osl + (size_t)(blockIdx.x * 64) * 256;

#pragma unroll
  for (int tt = 0; tt < 4; ++tt) {
    short8 xe[8], xl[8];
#pragma unroll
    for (int kc = 0; kc < 8; ++kc)
      xe[kc] = *(const short8*)(ae + (size_t)(tt * 16 + n) * 256 + kc * 32 + quad * 8);
#pragma unroll
    for (int kc = 0; kc < 8; ++kc)
      xl[kc] = *(const short8*)(al + (size_t)(tt * 16 + n) * 256 + kc * 32 + quad * 8);

    int tok = blockIdx.x * 64 + tt * 16 + n;
    f32x4 acc[2] = {{0.f, 0.f, 0.f, 0.f}, {0.f, 0.f, 0.f, 0.f}};
#pragma unroll
    for (int ct = 0; ct < 2; ++ct)
#pragma unroll
      for (int kc = 0; kc < 8; ++kc)
        acc[ct] = __builtin_amdgcn_mfma_f32_16x16x32_bf16(wfrag[ct][kc], xe[kc], acc[ct], 0, 0, 0);
#pragma unroll
    for (int ct = 0; ct < 2; ++ct)
#pragma unroll
      for (int kc = 0; kc < 8; ++kc)
        acc[ct] = __builtin_amdgcn_mfma_f32_16x16x32_bf16(wfrag[ct][kc], xl[kc], acc[ct], 0, 0, 0);
#pragma unroll
    for (int ct = 0; ct < 2; ++ct) {
      int c = cbase + ct * 16 + quad * 4;
      float* bp = (float*)&bt[ct];
      float4 st;
      st.x = acc[ct][0] + 2.0f * bp[0];
      st.y = acc[ct][1] + 2.0f * bp[1];
      st.z = acc[ct][2] + 2.0f * bp[2];
      st.w = acc[ct][3] + 2.0f * bp[3];
      *(float4*)(out + (size_t)tok * 256 + c) = st;
    }
  }
}

extern "C" void kernel_launch(void* const* d_in, const int* in_sizes, int n_in,
                              void* d_out, int out_size, void* d_ws, size_t ws_size,
                              hipStream_t stream) {
  const float* x   = (const float*)d_in[0];
  const float* lng = (const float*)d_in[1];
  const float* lnb = (const float*)d_in[2];
  const float* Wq  = (const float*)d_in[3];
  const float* bq  = (const float*)d_in[4];
  const float* Wk  = (const float*)d_in[5];
  const float* bk  = (const float*)d_in[6];
  const float* Wv  = (const float*)d_in[7];
  const float* bv  = (const float*)d_in[8];
  const float* Wo  = (const float*)d_in[9];
  const float* bo  = (const float*)d_in[10];
  float* out = (float*)d_out;

  ushort* ws = (ushort*)d_ws;
  const size_t XN  = (size_t)49152 * 256;      // 12,582,912
  const size_t QKV = (size_t)64 * 2048 * 32;   //  4,194,304
  ushort* xn     = ws;
  ushort* wbf    = xn + XN;          // [Wq|Wk|Wv|Wo] x 65536
  ushort* qb     = wbf + 4 * 65536;
  ushort* keb    = qb  + QKV;
  ushort* vTe    = keb + QKV;
  ushort* klb    = vTe + QKV;
  ushort* vTl    = klb + QKV;
  ushort* osum_e = vTl + QKV;
  ushort* osum_l = xn;               // alias: xn is dead after proj_kernel

  hipLaunchKernelGGL(ln_wcast_kernel, dim3(12544), dim3(256), 0, stream,
                     x, lng, lnb, Wq, Wk, Wv, Wo, xn, wbf);
  hipLaunchKernelGGL(proj_kernel, dim3(128, 2, 3), dim3(256), 0, stream,
                     xn, wbf, wbf + 65536, wbf + 131072, bq, bk, bv,
                     qb, keb, vTe, klb, vTl);
  hipLaunchKernelGGL(attn_kernel, dim3(8, 256), dim3(256), 0, stream,
                     qb, keb, vTe, klb, vTl, osum_e, osum_l);
  hipLaunchKernelGGL(outproj_kernel, dim3(256, 2), dim3(256), 0, stream,
                     osum_e, osum_l, wbf + 196608, bo, out);
}